// Round 3
// baseline (1646.315 us; speedup 1.0000x reference)
//
#include <hip/hip_runtime.h>
#include <math.h>

// Problem constants
#define NN 118   // nodes
#define EE 372   // edges
#define GG 2048  // B*T
#define DD 128   // hidden
#define TT 256   // seq len
#define BB 8     // batch
#define FD 512   // 4*D
#define DMAX 16  // padded per-node in-degree (overflow CSR handles the rest)

// LDS strides
#define XS 136   // xb/wt row stride in bf16 elems (16B-aligned rows)
#define HS 130   // hb row stride in f32

typedef short bf16x8 __attribute__((ext_vector_type(8)));
typedef float f32x4  __attribute__((ext_vector_type(4)));

__device__ __forceinline__ float frcp_(float x) { return __builtin_amdgcn_rcpf(x); }
__device__ __forceinline__ float sig_f(float x) { return frcp_(1.0f + __expf(-x)); }
__device__ __forceinline__ float tanh_f(float x) { return 1.0f - 2.0f * frcp_(__expf(2.0f * x) + 1.0f); }
__device__ __forceinline__ float silu_f(float x) { return x * frcp_(1.0f + __expf(-x)); }
__device__ __forceinline__ float sigmoidf_(float x) { return 1.0f / (1.0f + expf(-x)); }
__device__ __forceinline__ float siluf_(float x) { return x / (1.0f + expf(-x)); }

__device__ __forceinline__ unsigned short f2bf(float x) {
    unsigned int u = __float_as_uint(x);
    unsigned int r = (u + 0x7fffu + ((u >> 16) & 1u)) >> 16;
    return (unsigned short)r;
}
__device__ __forceinline__ float bf2f(unsigned short b) {
    return __uint_as_float(((unsigned int)b) << 16);
}

// ---------------------------------------------------------------------------
// prep: degree / padded fixed-degree edge table (premultiplied offsets) /
// overflow CSR / fused biases. 1 block.
// ---------------------------------------------------------------------------
__global__ void prep_kernel(const int* __restrict__ ei,
                            const float* __restrict__ bih0, const float* __restrict__ bhh0,
                            const float* __restrict__ bih1, const float* __restrict__ bhh1,
                            float* __restrict__ dinv, float* __restrict__ bias0,
                            float* __restrict__ bias1,
                            int* __restrict__ peoff, float* __restrict__ pecoef,
                            int* __restrict__ ovfn, int* __restrict__ ovfd,
                            int* __restrict__ ovfs, float* __restrict__ ovfc) {
    __shared__ int sflag;
    __shared__ int ssrc[EE], sdst[EE];
    __shared__ int scount[NN], scur[NN];
    __shared__ int srow[NN + 1];
    __shared__ float sinv[NN];
    __shared__ int scolw[EE];
    __shared__ float scoef[EE];
    __shared__ int sovfn;
    int tid = threadIdx.x;
    if (tid == 0) { sflag = 0; sovfn = 0; }
    __syncthreads();
    for (int i = tid; i < 2 * EE; i += blockDim.x)
        if ((i & 1) && ei[i] != 0) atomicOr(&sflag, 1);
    __syncthreads();
    bool m64 = (sflag == 0);
    for (int e = tid; e < EE; e += blockDim.x) {
        int s, d;
        if (m64) { s = ei[2 * e]; d = ei[2 * EE + 2 * e]; }
        else     { s = ei[e];     d = ei[EE + e]; }
        s = min(max(s, 0), NN - 1); d = min(max(d, 0), NN - 1);
        ssrc[e] = s; sdst[e] = d;
    }
    for (int n = tid; n < NN; n += blockDim.x) { scount[n] = 0; scur[n] = 0; }
    __syncthreads();
    for (int e = tid; e < EE; e += blockDim.x) atomicAdd(&scount[sdst[e]], 1);
    __syncthreads();
    if (tid == 0) {
        srow[0] = 0;
        for (int n = 0; n < NN; ++n) srow[n + 1] = srow[n] + scount[n];
    }
    __syncthreads();
    for (int n = tid; n < NN; n += blockDim.x) {
        float deg = 1.0f + (float)scount[n];
        sinv[n] = rsqrtf(deg);
        dinv[n] = 1.0f / deg;
    }
    __syncthreads();
    for (int e = tid; e < EE; e += blockDim.x) {
        int dn = sdst[e];
        int pos = srow[dn] + atomicAdd(&scur[dn], 1);
        scolw[pos] = ssrc[e];
        scoef[pos] = sinv[ssrc[e]] * sinv[dn];
    }
    __syncthreads();
    for (int i = tid; i < NN * DMAX; i += blockDim.x) {
        int n = i / DMAX, jj = i % DMAX;
        if (jj < scount[n]) {
            int e = srow[n] + jj;
            peoff[i] = scolw[e] * HS;
            pecoef[i] = scoef[e];
        } else {
            peoff[i] = 0;
            pecoef[i] = 0.0f;
        }
    }
    for (int n = tid; n < NN; n += blockDim.x) {
        int deg = scount[n];
        for (int jj = DMAX; jj < deg; ++jj) {
            int e = srow[n] + jj;
            int o = atomicAdd(&sovfn, 1);
            if (o < 64) { ovfd[o] = n; ovfs[o] = scolw[e] * HS; ovfc[o] = scoef[e]; }
        }
    }
    __syncthreads();
    if (tid == 0) *ovfn = min(sovfn, 64);
    for (int j = tid; j < FD; j += blockDim.x) {
        bias0[j] = bih0[j] + bhh0[j];
        bias1[j] = bih1[j] + bhh1[j];
    }
}

// ---------------------------------------------------------------------------
// W (K=128 x N=128, fp32) -> Wt bf16 [n][k] for MFMA B-frags
// ---------------------------------------------------------------------------
__global__ void convw_kernel(const float* __restrict__ W, unsigned short* __restrict__ out) {
    int i = blockIdx.x * 512 + threadIdx.x;  // 16384 total
    int n = i >> 7, k = i & 127;
    out[i] = f2bf(W[k * DD + n]);
}

// ---------------------------------------------------------------------------
// transpose (512,128) -> (128,512) so proj reads coalesced
// ---------------------------------------------------------------------------
__global__ void transpose_kernel(const float* __restrict__ in, float* __restrict__ out) {
    int idx = blockIdx.x * blockDim.x + threadIdx.x;  // 65536 total
    int j = idx >> 7, k = idx & 127;
    out[k * FD + j] = in[idx];
}

// ---------------------------------------------------------------------------
// GCN building blocks
// ---------------------------------------------------------------------------
__device__ __forceinline__ void load_wt(const unsigned short* __restrict__ Wtg,
                                        unsigned short* __restrict__ wt, int tid) {
    const ushort4* src = (const ushort4*)Wtg;
    for (int c = tid; c < 4096; c += 512) {
        int n = c >> 5, kq = c & 31;
        ushort4 v = src[c];
        *(ushort4*)(wt + n * XS + kq * 4) = v;
    }
}

// aggregate: fully-unrolled padded edge table (LDS), wave-uniform node,
// lane owns a fixed d-pair; biases in regs.
__device__ __forceinline__ void gcn_aggregate(const float* __restrict__ hb,
                                              unsigned short* __restrict__ xb,
                                              float bA, float bB,
                                              const float* __restrict__ dinvL,
                                              const int* __restrict__ peoffL,
                                              const float* __restrict__ pecoefL,
                                              int novf, const int* __restrict__ ovfd,
                                              const int* __restrict__ ovfs,
                                              const float* __restrict__ ovfc,
                                              int lane, int w) {
    int dd = lane * 2;
    for (int k = 0; k < 15; ++k) {
        int n = w + 8 * k;
        if (n >= NN) break;  // wave-uniform
        float2 v = *(const float2*)(hb + n * HS + dd);
        float di = dinvL[n];
        float a0 = v.x * di, a1 = v.y * di;
        const int* po = peoffL + n * DMAX;
        const float* pc = pecoefL + n * DMAX;
#pragma unroll
        for (int jj = 0; jj < DMAX; ++jj) {
            float c = pc[jj];
            float2 u = *(const float2*)(hb + po[jj] + dd);
            a0 += u.x * c; a1 += u.y * c;
        }
        for (int o = 0; o < novf; ++o) {  // almost always novf==0
            if (ovfd[o] == n) {
                float c = ovfc[o];
                float2 u = *(const float2*)(hb + ovfs[o] + dd);
                a0 += u.x * c; a1 += u.y * c;
            }
        }
        a0 = silu_f(a0 + bA);
        a1 = silu_f(a1 + bB);
        unsigned int pk = (unsigned int)f2bf(a0) | ((unsigned int)f2bf(a1) << 16);
        *(unsigned int*)(xb + n * XS + dd) = pk;
    }
}

// MFMA matmul: hb(f32) = xb(bf16) @ wt^T. 8 waves, each 64x32 tile.
__device__ __forceinline__ void gcn_mfma(const unsigned short* __restrict__ xb,
                                         const unsigned short* __restrict__ wt,
                                         float* __restrict__ hb, int tid) {
    int lane = tid & 63, w = tid >> 6;
    int lm = lane & 15, lq = lane >> 4;
    int wm = (w & 1) * 64;
    int wn = (w >> 1) * 32;
    f32x4 acc[4][2];
#pragma unroll
    for (int mt = 0; mt < 4; ++mt)
#pragma unroll
        for (int nt = 0; nt < 2; ++nt)
            acc[mt][nt] = (f32x4){0.f, 0.f, 0.f, 0.f};
#pragma unroll
    for (int kb = 0; kb < 4; ++kb) {
        int ko = kb * 32 + lq * 8;
        bf16x8 bfr0 = *(const bf16x8*)(wt + (wn + lm) * XS + ko);
        bf16x8 bfr1 = *(const bf16x8*)(wt + (wn + 16 + lm) * XS + ko);
#pragma unroll
        for (int mt = 0; mt < 4; ++mt) {
            bf16x8 af = *(const bf16x8*)(xb + (wm + mt * 16 + lm) * XS + ko);
            acc[mt][0] = __builtin_amdgcn_mfma_f32_16x16x32_bf16(af, bfr0, acc[mt][0], 0, 0, 0);
            acc[mt][1] = __builtin_amdgcn_mfma_f32_16x16x32_bf16(af, bfr1, acc[mt][1], 0, 0, 0);
        }
    }
#pragma unroll
    for (int mt = 0; mt < 4; ++mt)
#pragma unroll
        for (int nt = 0; nt < 2; ++nt)
#pragma unroll
            for (int i = 0; i < 4; ++i)
                hb[(wm + mt * 16 + lq * 4 + i) * HS + wn + nt * 16 + lm] = acc[mt][nt][i];
}

__global__ __launch_bounds__(512) void gcn_kernel(
    const float* __restrict__ xg, const float* __restrict__ scale, const float* __restrict__ shift,
    const float* __restrict__ W1, const float* __restrict__ b1,
    const float* __restrict__ b2, const float* __restrict__ b3,
    const unsigned short* __restrict__ Wt2g, const unsigned short* __restrict__ Wt3g,
    const float* __restrict__ dinvG, const int* __restrict__ peoffG,
    const float* __restrict__ pecoefG, const int* __restrict__ ovfnG,
    const int* __restrict__ ovfdG, const int* __restrict__ ovfsG,
    const float* __restrict__ ovfcG, float* __restrict__ emb) {
    extern __shared__ char smem[];
    unsigned short* xb = (unsigned short*)smem;             // 34816 B
    unsigned short* wt = (unsigned short*)(smem + 34816);   // 34816 B
    float* hb   = (float*)(smem + 69632);                   // 66560 B
    float* xinL = (float*)(smem + 136192);                  // 1424 B
    float* dinvL = (float*)(smem + 137616);                 // 480 B
    int*   peoffL = (int*)(smem + 138096);                  // 7552 B
    float* pecoefL = (float*)(smem + 145648);               // 7552 B
    int*   povL = (int*)(smem + 153200);                    // 512 B (ovfd 64 + ovfs 64)
    float* povcL = (float*)(smem + 153712);                 // 256 B -> end 153968
    int tid = threadIdx.x;
    int lane = tid & 63, w = tid >> 6;
    int g = blockIdx.x;

    // zero xb pad rows (118..127, cols 0..127)
    for (int i = tid; i < 10 * 64; i += 512) {
        int r = NN + (i >> 6), c = (i & 63) * 2;
        *(unsigned int*)(xb + r * XS + c) = 0u;
    }
    // stage input + tables
    float s0 = scale[0], s1 = scale[1], s2 = scale[2];
    float t0 = shift[0], t1 = shift[1], t2 = shift[2];
    const float* xrow = xg + (size_t)g * (NN * 3);
    for (int i = tid; i < NN * 3; i += 512) {
        int f = i % 3;
        float sc = (f == 0) ? s0 : ((f == 1) ? s1 : s2);
        float sf = (f == 0) ? t0 : ((f == 1) ? t1 : t2);
        xinL[i] = xrow[i] * sc + sf;
    }
    for (int i = tid; i < NN; i += 512) dinvL[i] = dinvG[i];
    for (int i = tid; i < NN * DMAX; i += 512) { peoffL[i] = peoffG[i]; pecoefL[i] = pecoefG[i]; }
    int novf = *ovfnG;
    for (int i = tid; i < 64; i += 512) { povL[i] = ovfdG[i]; povL[64 + i] = ovfsG[i]; povcL[i] = ovfcG[i]; }
    load_wt(Wt2g, wt, tid);
    // per-lane constants
    int dd = lane * 2;
    float b1a = b1[dd], b1b = b1[dd + 1];
    float b2a = b2[dd], b2b = b2[dd + 1];
    float b3a = b3[dd], b3b = b3[dd + 1];
    float2 w10 = *(const float2*)(W1 + dd);
    float2 w11 = *(const float2*)(W1 + DD + dd);
    float2 w12 = *(const float2*)(W1 + 2 * DD + dd);
    __syncthreads();
    // layer 1 (K=3): wave-per-node
    for (int k = 0; k < 15; ++k) {
        int n = w + 8 * k;
        if (n >= NN) break;
        float x0 = xinL[n * 3], x1 = xinL[n * 3 + 1], x2 = xinL[n * 3 + 2];
        float h0v = x0 * w10.x + x1 * w11.x + x2 * w12.x;
        float h1v = x0 * w10.y + x1 * w11.y + x2 * w12.y;
        *(float2*)(hb + n * HS + dd) = make_float2(h0v, h1v);
    }
    __syncthreads();
    gcn_aggregate(hb, xb, b1a, b1b, dinvL, peoffL, pecoefL, novf, povL, povL + 64, povcL, lane, w);
    __syncthreads();
    gcn_mfma(xb, wt, hb, tid);
    __syncthreads();
    load_wt(Wt3g, wt, tid);
    gcn_aggregate(hb, xb, b2a, b2b, dinvL, peoffL, pecoefL, novf, povL, povL + 64, povcL, lane, w);
    __syncthreads();
    gcn_mfma(xb, wt, hb, tid);
    __syncthreads();
    gcn_aggregate(hb, xb, b3a, b3b, dinvL, peoffL, pecoefL, novf, povL, povL + 64, povcL, lane, w);
    __syncthreads();
    // mean over nodes
    {
        int d = tid & 127, part = tid >> 7;
        int n0 = part * 30;
        int n1 = (n0 + 30 < NN) ? (n0 + 30) : NN;
        float s = 0.f;
        for (int n = n0; n < n1; ++n) s += bf2f(xb[n * XS + d]);
        hb[part * 128 + d] = s;
    }
    __syncthreads();
    if (tid < 128) {
        float s = hb[tid] + hb[128 + tid] + hb[256 + tid] + hb[384 + tid];
        emb[(size_t)g * DD + tid] = s * (1.0f / (float)NN);
    }
}

// ---------------------------------------------------------------------------
// proj: dst[g][j] = bias[j] + sum_k src[g][k] * WT[k][j]
// ---------------------------------------------------------------------------
__global__ __launch_bounds__(512) void proj_kernel(const float* __restrict__ src,
                                                   const float* __restrict__ WT,
                                                   const float* __restrict__ bias,
                                                   float* __restrict__ dst) {
    __shared__ __align__(16) float eL[DD];
    int g = blockIdx.x, tid = threadIdx.x;
    if (tid < DD) eL[tid] = src[(size_t)g * DD + tid];
    __syncthreads();
    float acc = bias[tid];
    const float* wt = WT + tid;
#pragma unroll 8
    for (int k = 0; k < DD; ++k) acc += eL[k] * wt[(size_t)k * FD];
    dst[(size_t)g * FD + tid] = acc;
}

// ---------------------------------------------------------------------------
// zero the pipeline flags (runs before scan_fused; dispatch boundary = fence)
// ---------------------------------------------------------------------------
__global__ void zeroflags_kernel(int* __restrict__ flagA, int* __restrict__ flagB) {
    if (threadIdx.x < BB) { flagA[threadIdx.x] = 0; flagB[threadIdx.x] = 0; }
}

// ---------------------------------------------------------------------------
// Fused 2-layer LSTM pipeline: 24 blocks = 8x(layer0 scan) + 8x(Wih1 proj)
// + 8x(layer1 scan), chained per batch through ws with agent-scope flags.
// All blocks co-resident (24 << 256 CUs). Bounded spin guard avoids hangs.
// ---------------------------------------------------------------------------
__global__ __launch_bounds__(512, 2) void scan_fused(
    const float* __restrict__ inp0,   // [B][T][512] gates0 pre-act (bias0 incl)
    const float* __restrict__ Whh0,   // [512][128]
    const float* __restrict__ Wih1,   // [512][128]
    const float* __restrict__ bias1,  // [512]
    const float* __restrict__ Whh1,   // [512][128]
    float* __restrict__ h0buf,        // [B][T][128]
    float* __restrict__ x1buf,        // [B][T][512]
    float* __restrict__ hfin,         // [B][128]
    int* __restrict__ flagA, int* __restrict__ flagB) {
    __shared__ __align__(16) float sh[DD];
    __shared__ float sg[FD];
    int stage = blockIdx.x >> 3, b = blockIdx.x & 7, j = threadIdx.x;

    if (stage == 1) {
        // ---- proj stage: x1_t = bias1 + Wih1 . h0_t ----
        float4 wreg[32];
        const float4* wp = ((const float4*)Wih1) + (size_t)j * 32;
#pragma unroll
        for (int q = 0; q < 32; ++q) wreg[q] = wp[q];
        float bj = bias1[j];
        float* xb_ = x1buf + (size_t)b * TT * FD;
        const float* hb_ = h0buf + (size_t)b * TT * DD;
        for (int t = 0; t < TT; ++t) {
            int guard = 0;
            while (__hip_atomic_load(&flagA[b], __ATOMIC_RELAXED, __HIP_MEMORY_SCOPE_AGENT) < t + 1) {
                if (++guard > (1 << 22)) break;
                __builtin_amdgcn_s_sleep(1);
            }
            __threadfence();
            if (j < DD) sh[j] = hb_[t * DD + j];
            __syncthreads();
            const float4* h4 = (const float4*)sh;
            float a0 = 0.f, a1 = 0.f, a2 = 0.f, a3 = 0.f;
#pragma unroll
            for (int q = 0; q < 32; ++q) {
                float4 hv = h4[q];
                a0 += hv.x * wreg[q].x;
                a1 += hv.y * wreg[q].y;
                a2 += hv.z * wreg[q].z;
                a3 += hv.w * wreg[q].w;
            }
            xb_[t * FD + j] = bj + ((a0 + a1) + (a2 + a3));
            __syncthreads();
            if (j == 0) {
                __threadfence();
                __hip_atomic_store(&flagB[b], t + 1, __ATOMIC_RELEASE, __HIP_MEMORY_SCOPE_AGENT);
            }
        }
        return;
    }

    // ---- scan stages (0 = layer0, 2 = layer1) ----
    const float* Whh = (stage == 0) ? Whh0 : Whh1;
    float4 wreg[32];
    const float4* wp = ((const float4*)Whh) + (size_t)j * 32;
#pragma unroll
    for (int q = 0; q < 32; ++q) wreg[q] = wp[q];
    float creg = 0.f;
    if (j < DD) sh[j] = 0.f;
    __syncthreads();
    bool isg = (j >= 2 * DD) && (j < 3 * DD);

    if (stage == 0) {
        const float* ib = inp0 + (size_t)b * TT * FD;
        float* hb_ = h0buf + (size_t)b * TT * DD;
        float gj = ib[j];
        for (int t = 0; t < TT; ++t) {
            float gnext = (t + 1 < TT) ? ib[(t + 1) * FD + j] : 0.f;  // prefetch
            const float4* h4 = (const float4*)sh;
            float a0 = 0.f, a1 = 0.f, a2 = 0.f, a3 = 0.f;
#pragma unroll
            for (int q = 0; q < 32; ++q) {
                float4 hv = h4[q];
                a0 += hv.x * wreg[q].x;
                a1 += hv.y * wreg[q].y;
                a2 += hv.z * wreg[q].z;
                a3 += hv.w * wreg[q].w;
            }
            float pre = gj + ((a0 + a1) + (a2 + a3));
            sg[j] = isg ? tanh_f(pre) : sig_f(pre);
            __syncthreads();
            if (j < DD) {
                float cn = sg[DD + j] * creg + sg[j] * sg[2 * DD + j];
                creg = cn;
                float hn = sg[3 * DD + j] * tanh_f(cn);
                sh[j] = hn;
                hb_[t * DD + j] = hn;
            }
            __syncthreads();
            if (j == 0) {
                __threadfence();
                __hip_atomic_store(&flagA[b], t + 1, __ATOMIC_RELEASE, __HIP_MEMORY_SCOPE_AGENT);
            }
            gj = gnext;
        }
    } else {
        const float* xb_ = x1buf + (size_t)b * TT * FD;
        for (int t = 0; t < TT; ++t) {
            int guard = 0;
            while (__hip_atomic_load(&flagB[b], __ATOMIC_RELAXED, __HIP_MEMORY_SCOPE_AGENT) < t + 1) {
                if (++guard > (1 << 22)) break;
                __builtin_amdgcn_s_sleep(1);
            }
            __threadfence();
            float xj = xb_[t * FD + j];  // issue early; consumed after dot
            const float4* h4 = (const float4*)sh;
            float a0 = 0.f, a1 = 0.f, a2 = 0.f, a3 = 0.f;
#pragma unroll
            for (int q = 0; q < 32; ++q) {
                float4 hv = h4[q];
                a0 += hv.x * wreg[q].x;
                a1 += hv.y * wreg[q].y;
                a2 += hv.z * wreg[q].z;
                a3 += hv.w * wreg[q].w;
            }
            float pre = xj + ((a0 + a1) + (a2 + a3));
            sg[j] = isg ? tanh_f(pre) : sig_f(pre);
            __syncthreads();
            if (j < DD) {
                float cn = sg[DD + j] * creg + sg[j] * sg[2 * DD + j];
                creg = cn;
                float hn = sg[3 * DD + j] * tanh_f(cn);
                sh[j] = hn;
                if (t == TT - 1) hfin[b * DD + j] = hn;
            }
            __syncthreads();
        }
    }
}

// ---------------------------------------------------------------------------
// head MLP on final hidden state. 1 block.
// ---------------------------------------------------------------------------
__global__ void head_kernel(const float* __restrict__ hfin,
                            const float* __restrict__ hW1, const float* __restrict__ hb1,
                            const float* __restrict__ hW2, const float* __restrict__ hb2,
                            const float* __restrict__ hW3, const float* __restrict__ hb3,
                            float* __restrict__ out) {
    __shared__ float fh[BB * DD];
    __shared__ float y1[BB * DD];
    __shared__ float y2[BB * 64];
    int tid = threadIdx.x;
    for (int i = tid; i < BB * DD; i += 256) fh[i] = hfin[i];
    __syncthreads();
    for (int i = tid; i < BB * DD; i += 256) {
        int bb = i >> 7, jj = i & 127;
        float acc = hb1[jj];
        for (int k = 0; k < DD; ++k) acc += fh[(bb << 7) + k] * hW1[(k << 7) + jj];
        y1[i] = siluf_(acc);
    }
    __syncthreads();
    for (int i = tid; i < BB * 64; i += 256) {
        int bb = i >> 6, jj = i & 63;
        float acc = hb2[jj];
        for (int k = 0; k < DD; ++k) acc += y1[(bb << 7) + k] * hW2[(k << 6) + jj];
        y2[i] = siluf_(acc);
    }
    __syncthreads();
    if (tid < BB * 2) {
        int bb = tid >> 1, m = tid & 1;
        float acc = hb3[m];
        for (int k = 0; k < 64; ++k) acc += y2[(bb << 6) + k] * hW3[k * 2 + m];
        float sp = fmaxf(acc, 0.f) + log1pf(expf(-fabsf(acc)));
        out[tid] = sp + 1e-6f;
    }
}

// ---------------------------------------------------------------------------
extern "C" void kernel_launch(void* const* d_in, const int* in_sizes, int n_in,
                              void* d_out, int out_size, void* d_ws, size_t ws_size,
                              hipStream_t stream) {
    const float* snap  = (const float*)d_in[0];
    const int*   edges = (const int*)d_in[1];
    const float* scale = (const float*)d_in[2];
    const float* shift = (const float*)d_in[3];
    const float* W1 = (const float*)d_in[4];
    const float* b1 = (const float*)d_in[5];
    const float* W2 = (const float*)d_in[6];
    const float* b2 = (const float*)d_in[7];
    const float* W3 = (const float*)d_in[8];
    const float* b3 = (const float*)d_in[9];
    const float* Wih0 = (const float*)d_in[10];
    const float* Whh0 = (const float*)d_in[11];
    const float* bih0 = (const float*)d_in[12];
    const float* bhh0 = (const float*)d_in[13];
    const float* Wih1 = (const float*)d_in[14];
    const float* Whh1 = (const float*)d_in[15];
    const float* bih1 = (const float*)d_in[16];
    const float* bhh1 = (const float*)d_in[17];
    const float* hW1 = (const float*)d_in[18];
    const float* hb1 = (const float*)d_in[19];
    const float* hW2 = (const float*)d_in[20];
    const float* hb2 = (const float*)d_in[21];
    const float* hW3 = (const float*)d_in[22];
    const float* hb3 = (const float*)d_in[23];

    // workspace carve (float indices); total ~10.8 MB
    float* ws = (float*)d_ws;
    float* dinv   = ws + 0;                      // 128
    float* bias0  = ws + 128;                    // 512
    float* bias1  = ws + 640;                    // 512
    int*   peoff  = (int*)(ws + 1152);           // 1888
    float* pecoef = ws + 3040;                   // 1888
    int*   ovfn   = (int*)(ws + 4928);           // 1 (+pad)
    int*   ovfd   = (int*)(ws + 4932);           // 64
    int*   ovfs   = (int*)(ws + 4996);           // 64
    float* ovfc   = ws + 5060;                   // 64 -> 5124
    unsigned short* Wt2g = (unsigned short*)(ws + 5248);   // 8192 f
    unsigned short* Wt3g = (unsigned short*)(ws + 13440);  // 8192 f
    float* WT0   = ws + 21632;                   // 65536
    float* emb   = ws + 87168;                   // 262144
    float* inp0  = ws + 349312;                  // 1048576
    float* h0buf = ws + 1397888;                 // 262144
    float* x1buf = ws + 1660032;                 // 1048576
    float* hfin  = ws + 2708608;                 // 1024
    int*   flagA = (int*)(ws + 2709632);         // 8
    int*   flagB = (int*)(ws + 2709640);         // 8

    const int smem_gcn = 153968;
    hipFuncSetAttribute((const void*)gcn_kernel,
                        hipFuncAttributeMaxDynamicSharedMemorySize, smem_gcn);

    prep_kernel<<<1, 256, 0, stream>>>(edges, bih0, bhh0, bih1, bhh1,
                                       dinv, bias0, bias1, peoff, pecoef,
                                       ovfn, ovfd, ovfs, ovfc);
    convw_kernel<<<32, 512, 0, stream>>>(W2, Wt2g);
    convw_kernel<<<32, 512, 0, stream>>>(W3, Wt3g);
    transpose_kernel<<<128, 512, 0, stream>>>(Wih0, WT0);
    gcn_kernel<<<GG, 512, smem_gcn, stream>>>(snap, scale, shift, W1, b1, b2, b3,
                                              Wt2g, Wt3g, dinv, peoff, pecoef,
                                              ovfn, ovfd, ovfs, ovfc, emb);
    proj_kernel<<<GG, 512, 0, stream>>>(emb, WT0, bias0, inp0);
    zeroflags_kernel<<<1, 64, 0, stream>>>(flagA, flagB);
    scan_fused<<<3 * BB, 512, 0, stream>>>(inp0, Whh0, Wih1, bias1, Whh1,
                                           h0buf, x1buf, hfin, flagA, flagB);
    head_kernel<<<1, 256, 0, stream>>>(hfin, hW1, hb1, hW2, hb2, hW3, hb3, (float*)d_out);
}

// Round 4
// 832.454 us; speedup vs baseline: 1.9777x; 1.9777x over previous
//
#include <hip/hip_runtime.h>
#include <math.h>

// Problem constants
#define NN 118   // nodes
#define EE 372   // edges
#define GG 2048  // B*T
#define DD 128   // hidden
#define TT 256   // seq len
#define BB 8     // batch
#define FD 512   // 4*D
#define DMAX 16  // padded per-node in-degree (overflow handles the rest)

// LDS strides
#define XS 136   // xb/wt row stride in bf16 elems (16B-aligned rows)
#define HS 130   // hb row stride in f32

typedef short bf16x8 __attribute__((ext_vector_type(8)));
typedef float f32x4  __attribute__((ext_vector_type(4)));

__device__ __forceinline__ float frcp_(float x) { return __builtin_amdgcn_rcpf(x); }
__device__ __forceinline__ float sig_f(float x) { return frcp_(1.0f + __expf(-x)); }
__device__ __forceinline__ float tanh_f(float x) { return 1.0f - 2.0f * frcp_(__expf(2.0f * x) + 1.0f); }
__device__ __forceinline__ float silu_f(float x) { return x * frcp_(1.0f + __expf(-x)); }
__device__ __forceinline__ float sigmoidf_(float x) { return 1.0f / (1.0f + expf(-x)); }
__device__ __forceinline__ float siluf_(float x) { return x / (1.0f + expf(-x)); }

// Barrier that drains only LDS ops (lgkmcnt), NOT vmcnt: global stores stay
// fire-and-forget and prefetch loads stay in flight across the barrier.
// Safe here because all cross-thread data flows through LDS (global->VGPR
// paths get compiler-inserted vmcnt waits at the register use).
__device__ __forceinline__ void bar_lds() {
    asm volatile("s_waitcnt lgkmcnt(0)\n\ts_barrier" ::: "memory");
}

__device__ __forceinline__ unsigned short f2bf(float x) {
    unsigned int u = __float_as_uint(x);
    unsigned int r = (u + 0x7fffu + ((u >> 16) & 1u)) >> 16;
    return (unsigned short)r;
}
__device__ __forceinline__ float bf2f(unsigned short b) {
    return __uint_as_float(((unsigned int)b) << 16);
}

// ---------------------------------------------------------------------------
// prep: degree / padded fixed-degree edge table (premultiplied offsets) /
// overflow list / fused biases. 1 block.
// ---------------------------------------------------------------------------
__global__ void prep_kernel(const int* __restrict__ ei,
                            const float* __restrict__ bih0, const float* __restrict__ bhh0,
                            const float* __restrict__ bih1, const float* __restrict__ bhh1,
                            float* __restrict__ dinv, float* __restrict__ bias0,
                            float* __restrict__ bias1,
                            int* __restrict__ peoff, float* __restrict__ pecoef,
                            int* __restrict__ ovfn, int* __restrict__ ovfd,
                            int* __restrict__ ovfs, float* __restrict__ ovfc) {
    __shared__ int sflag;
    __shared__ int ssrc[EE], sdst[EE];
    __shared__ int scount[NN], scur[NN];
    __shared__ int srow[NN + 1];
    __shared__ float sinv[NN];
    __shared__ int scolw[EE];
    __shared__ float scoef[EE];
    __shared__ int sovfn;
    int tid = threadIdx.x;
    if (tid == 0) { sflag = 0; sovfn = 0; }
    __syncthreads();
    for (int i = tid; i < 2 * EE; i += blockDim.x)
        if ((i & 1) && ei[i] != 0) atomicOr(&sflag, 1);
    __syncthreads();
    bool m64 = (sflag == 0);
    for (int e = tid; e < EE; e += blockDim.x) {
        int s, d;
        if (m64) { s = ei[2 * e]; d = ei[2 * EE + 2 * e]; }
        else     { s = ei[e];     d = ei[EE + e]; }
        s = min(max(s, 0), NN - 1); d = min(max(d, 0), NN - 1);
        ssrc[e] = s; sdst[e] = d;
    }
    for (int n = tid; n < NN; n += blockDim.x) { scount[n] = 0; scur[n] = 0; }
    __syncthreads();
    for (int e = tid; e < EE; e += blockDim.x) atomicAdd(&scount[sdst[e]], 1);
    __syncthreads();
    if (tid == 0) {
        srow[0] = 0;
        for (int n = 0; n < NN; ++n) srow[n + 1] = srow[n] + scount[n];
    }
    __syncthreads();
    for (int n = tid; n < NN; n += blockDim.x) {
        float deg = 1.0f + (float)scount[n];
        sinv[n] = rsqrtf(deg);
        dinv[n] = 1.0f / deg;
    }
    __syncthreads();
    for (int e = tid; e < EE; e += blockDim.x) {
        int dn = sdst[e];
        int pos = srow[dn] + atomicAdd(&scur[dn], 1);
        scolw[pos] = ssrc[e];
        scoef[pos] = sinv[ssrc[e]] * sinv[dn];
    }
    __syncthreads();
    for (int i = tid; i < NN * DMAX; i += blockDim.x) {
        int n = i / DMAX, jj = i % DMAX;
        if (jj < scount[n]) {
            int e = srow[n] + jj;
            peoff[i] = scolw[e] * HS;
            pecoef[i] = scoef[e];
        } else {
            peoff[i] = 0;
            pecoef[i] = 0.0f;
        }
    }
    for (int n = tid; n < NN; n += blockDim.x) {
        int deg = scount[n];
        for (int jj = DMAX; jj < deg; ++jj) {
            int e = srow[n] + jj;
            int o = atomicAdd(&sovfn, 1);
            if (o < 64) { ovfd[o] = n; ovfs[o] = scolw[e] * HS; ovfc[o] = scoef[e]; }
        }
    }
    __syncthreads();
    if (tid == 0) *ovfn = min(sovfn, 64);
    for (int j = tid; j < FD; j += blockDim.x) {
        bias0[j] = bih0[j] + bhh0[j];
        bias1[j] = bih1[j] + bhh1[j];
    }
}

// ---------------------------------------------------------------------------
// W (K=128 x N=128, fp32) -> Wt bf16 [n][k] for MFMA B-frags
// ---------------------------------------------------------------------------
__global__ void convw_kernel(const float* __restrict__ W, unsigned short* __restrict__ out) {
    int i = blockIdx.x * 512 + threadIdx.x;  // 16384 total
    int n = i >> 7, k = i & 127;
    out[i] = f2bf(W[k * DD + n]);
}

// ---------------------------------------------------------------------------
// transpose (512,128) -> (128,512) so proj reads coalesced
// ---------------------------------------------------------------------------
__global__ void transpose_kernel(const float* __restrict__ in, float* __restrict__ out) {
    int idx = blockIdx.x * blockDim.x + threadIdx.x;  // 65536 total
    int j = idx >> 7, k = idx & 127;
    out[k * FD + j] = in[idx];
}

// ---------------------------------------------------------------------------
// GCN building blocks
// ---------------------------------------------------------------------------
__device__ __forceinline__ void load_wt(const unsigned short* __restrict__ Wtg,
                                        unsigned short* __restrict__ wt, int tid) {
    const ushort4* src = (const ushort4*)Wtg;
    for (int c = tid; c < 4096; c += 512) {
        int n = c >> 5, kq = c & 31;
        ushort4 v = src[c];
        *(ushort4*)(wt + n * XS + kq * 4) = v;
    }
}

// aggregate: fully-unrolled padded edge table (LDS), wave-uniform node,
// lane owns a fixed d-pair; biases in regs.
__device__ __forceinline__ void gcn_aggregate(const float* __restrict__ hb,
                                              unsigned short* __restrict__ xb,
                                              float bA, float bB,
                                              const float* __restrict__ dinvL,
                                              const int* __restrict__ peoffL,
                                              const float* __restrict__ pecoefL,
                                              int novf, const int* __restrict__ ovfd,
                                              const int* __restrict__ ovfs,
                                              const float* __restrict__ ovfc,
                                              int lane, int w) {
    int dd = lane * 2;
    for (int k = 0; k < 15; ++k) {
        int n = w + 8 * k;
        if (n >= NN) break;  // wave-uniform
        float2 v = *(const float2*)(hb + n * HS + dd);
        float di = dinvL[n];
        float a0 = v.x * di, a1 = v.y * di;
        const int* po = peoffL + n * DMAX;
        const float* pc = pecoefL + n * DMAX;
#pragma unroll
        for (int jj = 0; jj < DMAX; ++jj) {
            float c = pc[jj];
            float2 u = *(const float2*)(hb + po[jj] + dd);
            a0 += u.x * c; a1 += u.y * c;
        }
        for (int o = 0; o < novf; ++o) {  // almost always novf==0
            if (ovfd[o] == n) {
                float c = ovfc[o];
                float2 u = *(const float2*)(hb + ovfs[o] + dd);
                a0 += u.x * c; a1 += u.y * c;
            }
        }
        a0 = silu_f(a0 + bA);
        a1 = silu_f(a1 + bB);
        unsigned int pk = (unsigned int)f2bf(a0) | ((unsigned int)f2bf(a1) << 16);
        *(unsigned int*)(xb + n * XS + dd) = pk;
    }
}

// MFMA matmul: hb(f32) = xb(bf16) @ wt^T. 8 waves, each 64x32 tile.
__device__ __forceinline__ void gcn_mfma(const unsigned short* __restrict__ xb,
                                         const unsigned short* __restrict__ wt,
                                         float* __restrict__ hb, int tid) {
    int lane = tid & 63, w = tid >> 6;
    int lm = lane & 15, lq = lane >> 4;
    int wm = (w & 1) * 64;
    int wn = (w >> 1) * 32;
    f32x4 acc[4][2];
#pragma unroll
    for (int mt = 0; mt < 4; ++mt)
#pragma unroll
        for (int nt = 0; nt < 2; ++nt)
            acc[mt][nt] = (f32x4){0.f, 0.f, 0.f, 0.f};
#pragma unroll
    for (int kb = 0; kb < 4; ++kb) {
        int ko = kb * 32 + lq * 8;
        bf16x8 bfr0 = *(const bf16x8*)(wt + (wn + lm) * XS + ko);
        bf16x8 bfr1 = *(const bf16x8*)(wt + (wn + 16 + lm) * XS + ko);
#pragma unroll
        for (int mt = 0; mt < 4; ++mt) {
            bf16x8 af = *(const bf16x8*)(xb + (wm + mt * 16 + lm) * XS + ko);
            acc[mt][0] = __builtin_amdgcn_mfma_f32_16x16x32_bf16(af, bfr0, acc[mt][0], 0, 0, 0);
            acc[mt][1] = __builtin_amdgcn_mfma_f32_16x16x32_bf16(af, bfr1, acc[mt][1], 0, 0, 0);
        }
    }
#pragma unroll
    for (int mt = 0; mt < 4; ++mt)
#pragma unroll
        for (int nt = 0; nt < 2; ++nt)
#pragma unroll
            for (int i = 0; i < 4; ++i)
                hb[(wm + mt * 16 + lq * 4 + i) * HS + wn + nt * 16 + lm] = acc[mt][nt][i];
}

__global__ __launch_bounds__(512) void gcn_kernel(
    const float* __restrict__ xg, const float* __restrict__ scale, const float* __restrict__ shift,
    const float* __restrict__ W1, const float* __restrict__ b1,
    const float* __restrict__ b2, const float* __restrict__ b3,
    const unsigned short* __restrict__ Wt2g, const unsigned short* __restrict__ Wt3g,
    const float* __restrict__ dinvG, const int* __restrict__ peoffG,
    const float* __restrict__ pecoefG, const int* __restrict__ ovfnG,
    const int* __restrict__ ovfdG, const int* __restrict__ ovfsG,
    const float* __restrict__ ovfcG, float* __restrict__ emb) {
    extern __shared__ char smem[];
    unsigned short* xb = (unsigned short*)smem;             // 34816 B
    unsigned short* wt = (unsigned short*)(smem + 34816);   // 34816 B
    float* hb   = (float*)(smem + 69632);                   // 66560 B
    float* xinL = (float*)(smem + 136192);                  // 1424 B
    float* dinvL = (float*)(smem + 137616);                 // 480 B
    int*   peoffL = (int*)(smem + 138096);                  // 7552 B
    float* pecoefL = (float*)(smem + 145648);               // 7552 B
    int*   povL = (int*)(smem + 153200);                    // 512 B (ovfd 64 + ovfs 64)
    float* povcL = (float*)(smem + 153712);                 // 256 B -> end 153968
    int tid = threadIdx.x;
    int lane = tid & 63, w = tid >> 6;
    int g = blockIdx.x;

    // zero xb pad rows (118..127)
    for (int i = tid; i < 10 * 64; i += 512) {
        int r = NN + (i >> 6), c = (i & 63) * 2;
        *(unsigned int*)(xb + r * XS + c) = 0u;
    }
    // stage input + tables
    float s0 = scale[0], s1 = scale[1], s2 = scale[2];
    float t0 = shift[0], t1 = shift[1], t2 = shift[2];
    const float* xrow = xg + (size_t)g * (NN * 3);
    for (int i = tid; i < NN * 3; i += 512) {
        int f = i % 3;
        float sc = (f == 0) ? s0 : ((f == 1) ? s1 : s2);
        float sf = (f == 0) ? t0 : ((f == 1) ? t1 : t2);
        xinL[i] = xrow[i] * sc + sf;
    }
    for (int i = tid; i < NN; i += 512) dinvL[i] = dinvG[i];
    for (int i = tid; i < NN * DMAX; i += 512) { peoffL[i] = peoffG[i]; pecoefL[i] = pecoefG[i]; }
    int novf = *ovfnG;
    for (int i = tid; i < 64; i += 512) { povL[i] = ovfdG[i]; povL[64 + i] = ovfsG[i]; povcL[i] = ovfcG[i]; }
    load_wt(Wt2g, wt, tid);
    // per-lane constants
    int dd = lane * 2;
    float b1a = b1[dd], b1b = b1[dd + 1];
    float b2a = b2[dd], b2b = b2[dd + 1];
    float b3a = b3[dd], b3b = b3[dd + 1];
    float2 w10 = *(const float2*)(W1 + dd);
    float2 w11 = *(const float2*)(W1 + DD + dd);
    float2 w12 = *(const float2*)(W1 + 2 * DD + dd);
    bar_lds();
    // layer 1 (K=3): wave-per-node
    for (int k = 0; k < 15; ++k) {
        int n = w + 8 * k;
        if (n >= NN) break;
        float x0 = xinL[n * 3], x1 = xinL[n * 3 + 1], x2 = xinL[n * 3 + 2];
        float h0v = x0 * w10.x + x1 * w11.x + x2 * w12.x;
        float h1v = x0 * w10.y + x1 * w11.y + x2 * w12.y;
        *(float2*)(hb + n * HS + dd) = make_float2(h0v, h1v);
    }
    bar_lds();
    gcn_aggregate(hb, xb, b1a, b1b, dinvL, peoffL, pecoefL, novf, povL, povL + 64, povcL, lane, w);
    bar_lds();
    gcn_mfma(xb, wt, hb, tid);
    bar_lds();
    load_wt(Wt3g, wt, tid);
    gcn_aggregate(hb, xb, b2a, b2b, dinvL, peoffL, pecoefL, novf, povL, povL + 64, povcL, lane, w);
    bar_lds();
    gcn_mfma(xb, wt, hb, tid);
    bar_lds();
    gcn_aggregate(hb, xb, b3a, b3b, dinvL, peoffL, pecoefL, novf, povL, povL + 64, povcL, lane, w);
    bar_lds();
    // mean over nodes
    {
        int d = tid & 127, part = tid >> 7;
        int n0 = part * 30;
        int n1 = (n0 + 30 < NN) ? (n0 + 30) : NN;
        float s = 0.f;
        for (int n = n0; n < n1; ++n) s += bf2f(xb[n * XS + d]);
        hb[part * 128 + d] = s;
    }
    bar_lds();
    if (tid < 128) {
        float s = hb[tid] + hb[128 + tid] + hb[256 + tid] + hb[384 + tid];
        emb[(size_t)g * DD + tid] = s * (1.0f / (float)NN);
    }
}

// ---------------------------------------------------------------------------
// proj: dst[g][j] = bias[j] + sum_k src[g][k] * WT[k][j]
// ---------------------------------------------------------------------------
__global__ __launch_bounds__(512) void proj_kernel(const float* __restrict__ src,
                                                   const float* __restrict__ WT,
                                                   const float* __restrict__ bias,
                                                   float* __restrict__ dst) {
    __shared__ __align__(16) float eL[DD];
    int g = blockIdx.x, tid = threadIdx.x;
    if (tid < DD) eL[tid] = src[(size_t)g * DD + tid];
    __syncthreads();
    float acc = bias[tid];
    const float* wt = WT + tid;
#pragma unroll 8
    for (int k = 0; k < DD; ++k) acc += eL[k] * wt[(size_t)k * FD];
    dst[(size_t)g * FD + tid] = acc;
}

// ---------------------------------------------------------------------------
// LSTM scan: one workgroup per batch element. Whh row j register-resident.
// lgkm-only barriers: the per-step global h-store and the t+1 input prefetch
// stay in flight across barriers (no vmcnt(0) drain).
// full=1: write whole h sequence; full=0: write only final h (B x 128).
// ---------------------------------------------------------------------------
__global__ __launch_bounds__(512, 2) void scan_kernel(const float* __restrict__ inp,
                                                      const float* __restrict__ Whh,
                                                      float* __restrict__ hout, int full) {
    __shared__ __align__(16) float sh[DD];
    __shared__ float sg[FD];
    int b = blockIdx.x, j = threadIdx.x;
    float4 wreg[32];
    const float4* wp = ((const float4*)Whh) + (size_t)j * 32;
#pragma unroll
    for (int q = 0; q < 32; ++q) wreg[q] = wp[q];
    float creg = 0.f;
    if (j < DD) sh[j] = 0.f;
    bar_lds();
    const float* ib = inp + (size_t)b * TT * FD;
    float* hb_ = hout + (size_t)b * (full ? TT * DD : DD);
    bool isg = (j >= 2 * DD) && (j < 3 * DD);
    float gj = ib[j];
    for (int t = 0; t < TT; ++t) {
        float gnext = (t + 1 < TT) ? ib[(t + 1) * FD + j] : 0.f;  // prefetch
        const float4* h4 = (const float4*)sh;
        float a0 = 0.f, a1 = 0.f, a2 = 0.f, a3 = 0.f;
#pragma unroll
        for (int q = 0; q < 32; ++q) {
            float4 hv = h4[q];
            a0 += hv.x * wreg[q].x;
            a1 += hv.y * wreg[q].y;
            a2 += hv.z * wreg[q].z;
            a3 += hv.w * wreg[q].w;
        }
        float pre = gj + ((a0 + a1) + (a2 + a3));
        sg[j] = isg ? tanh_f(pre) : sig_f(pre);
        bar_lds();
        if (j < DD) {
            float cn = sg[DD + j] * creg + sg[j] * sg[2 * DD + j];
            creg = cn;
            float hn = sg[3 * DD + j] * tanh_f(cn);
            sh[j] = hn;
            if (full) hb_[t * DD + j] = hn;       // fire-and-forget
            else if (t == TT - 1) hb_[j] = hn;
        }
        bar_lds();
        gj = gnext;
    }
}

// ---------------------------------------------------------------------------
// head MLP on final hidden state. 1 block.
// ---------------------------------------------------------------------------
__global__ void head_kernel(const float* __restrict__ hfin,
                            const float* __restrict__ hW1, const float* __restrict__ hb1,
                            const float* __restrict__ hW2, const float* __restrict__ hb2,
                            const float* __restrict__ hW3, const float* __restrict__ hb3,
                            float* __restrict__ out) {
    __shared__ float fh[BB * DD];
    __shared__ float y1[BB * DD];
    __shared__ float y2[BB * 64];
    int tid = threadIdx.x;
    for (int i = tid; i < BB * DD; i += 256) fh[i] = hfin[i];
    __syncthreads();
    for (int i = tid; i < BB * DD; i += 256) {
        int bb = i >> 7, jj = i & 127;
        float acc = hb1[jj];
        for (int k = 0; k < DD; ++k) acc += fh[(bb << 7) + k] * hW1[(k << 7) + jj];
        y1[i] = siluf_(acc);
    }
    __syncthreads();
    for (int i = tid; i < BB * 64; i += 256) {
        int bb = i >> 6, jj = i & 63;
        float acc = hb2[jj];
        for (int k = 0; k < DD; ++k) acc += y1[(bb << 7) + k] * hW2[(k << 6) + jj];
        y2[i] = siluf_(acc);
    }
    __syncthreads();
    if (tid < BB * 2) {
        int bb = tid >> 1, m = tid & 1;
        float acc = hb3[m];
        for (int k = 0; k < 64; ++k) acc += y2[(bb << 6) + k] * hW3[k * 2 + m];
        float sp = fmaxf(acc, 0.f) + log1pf(expf(-fabsf(acc)));
        out[tid] = sp + 1e-6f;
    }
}

// ---------------------------------------------------------------------------
extern "C" void kernel_launch(void* const* d_in, const int* in_sizes, int n_in,
                              void* d_out, int out_size, void* d_ws, size_t ws_size,
                              hipStream_t stream) {
    const float* snap  = (const float*)d_in[0];
    const int*   edges = (const int*)d_in[1];
    const float* scale = (const float*)d_in[2];
    const float* shift = (const float*)d_in[3];
    const float* W1 = (const float*)d_in[4];
    const float* b1 = (const float*)d_in[5];
    const float* W2 = (const float*)d_in[6];
    const float* b2 = (const float*)d_in[7];
    const float* W3 = (const float*)d_in[8];
    const float* b3 = (const float*)d_in[9];
    const float* Wih0 = (const float*)d_in[10];
    const float* Whh0 = (const float*)d_in[11];
    const float* bih0 = (const float*)d_in[12];
    const float* bhh0 = (const float*)d_in[13];
    const float* Wih1 = (const float*)d_in[14];
    const float* Whh1 = (const float*)d_in[15];
    const float* bih1 = (const float*)d_in[16];
    const float* bhh1 = (const float*)d_in[17];
    const float* hW1 = (const float*)d_in[18];
    const float* hb1 = (const float*)d_in[19];
    const float* hW2 = (const float*)d_in[20];
    const float* hb2 = (const float*)d_in[21];
    const float* hW3 = (const float*)d_in[22];
    const float* hb3 = (const float*)d_in[23];

    // workspace carve (float indices); ~6.9 MB
    float* ws = (float*)d_ws;
    float* dinv   = ws + 0;                      // 128
    float* bias0  = ws + 128;                    // 512
    float* bias1  = ws + 640;                    // 512
    int*   peoff  = (int*)(ws + 1152);           // 1888
    float* pecoef = ws + 3040;                   // 1888
    int*   ovfn   = (int*)(ws + 4928);           // 1 (+pad)
    int*   ovfd   = (int*)(ws + 4932);           // 64
    int*   ovfs   = (int*)(ws + 4996);           // 64
    float* ovfc   = ws + 5060;                   // 64
    unsigned short* Wt2g = (unsigned short*)(ws + 5248);   // 8192 f
    unsigned short* Wt3g = (unsigned short*)(ws + 13440);  // 8192 f
    float* WT0   = ws + 21632;                   // 65536
    float* WT1   = ws + 87168;                   // 65536
    float* emb   = ws + 152704;                  // 262144
    float* inp   = ws + 414848;                  // 1048576 (both LSTM layers)
    float* h0seq = ws + 1463424;                 // 262144
    float* hfin  = ws + 1725568;                 // 1024

    const int smem_gcn = 153968;
    hipFuncSetAttribute((const void*)gcn_kernel,
                        hipFuncAttributeMaxDynamicSharedMemorySize, smem_gcn);

    prep_kernel<<<1, 256, 0, stream>>>(edges, bih0, bhh0, bih1, bhh1,
                                       dinv, bias0, bias1, peoff, pecoef,
                                       ovfn, ovfd, ovfs, ovfc);
    convw_kernel<<<32, 512, 0, stream>>>(W2, Wt2g);
    convw_kernel<<<32, 512, 0, stream>>>(W3, Wt3g);
    transpose_kernel<<<128, 512, 0, stream>>>(Wih0, WT0);
    transpose_kernel<<<128, 512, 0, stream>>>(Wih1, WT1);
    gcn_kernel<<<GG, 512, smem_gcn, stream>>>(snap, scale, shift, W1, b1, b2, b3,
                                              Wt2g, Wt3g, dinv, peoff, pecoef,
                                              ovfn, ovfd, ovfs, ovfc, emb);
    proj_kernel<<<GG, 512, 0, stream>>>(emb, WT0, bias0, inp);
    scan_kernel<<<BB, 512, 0, stream>>>(inp, Whh0, h0seq, 1);
    proj_kernel<<<GG, 512, 0, stream>>>(h0seq, WT1, bias1, inp);
    scan_kernel<<<BB, 512, 0, stream>>>(inp, Whh1, hfin, 0);
    head_kernel<<<1, 256, 0, stream>>>(hfin, hW1, hb1, hW2, hb2, hW3, hb3, (float*)d_out);
}

// Round 5
// 710.290 us; speedup vs baseline: 2.3178x; 1.1720x over previous
//
#include <hip/hip_runtime.h>
#include <math.h>

// Problem constants
#define NN 118   // nodes
#define EE 372   // edges
#define GG 2048  // B*T
#define DD 128   // hidden
#define TT 256   // seq len
#define BB 8     // batch
#define FD 512   // 4*D

// LDS stride for bf16 matrices (rows 16B-aligned, +8 pad elems -> 2-way-max bank aliasing)
#define XS 136

typedef short bf16x8 __attribute__((ext_vector_type(8)));
typedef float f32x4  __attribute__((ext_vector_type(4)));

__device__ __forceinline__ float frcp_(float x) { return __builtin_amdgcn_rcpf(x); }
__device__ __forceinline__ float sig_f(float x) { return frcp_(1.0f + __expf(-x)); }
__device__ __forceinline__ float tanh_f(float x) { return 1.0f - 2.0f * frcp_(__expf(2.0f * x) + 1.0f); }
__device__ __forceinline__ float silu_f(float x) { return x * frcp_(1.0f + __expf(-x)); }
__device__ __forceinline__ float siluf_(float x) { return x / (1.0f + expf(-x)); }

// Barrier draining only LDS ops (lgkmcnt), not vmcnt: global stores stay
// fire-and-forget, prefetch loads stay in flight. Safe: all cross-thread data
// flows through LDS (global->VGPR uses get compiler vmcnt waits).
__device__ __forceinline__ void bar_lds() {
    asm volatile("s_waitcnt lgkmcnt(0)\n\ts_barrier" ::: "memory");
}

__device__ __forceinline__ unsigned short f2bf(float x) {
    unsigned int u = __float_as_uint(x);
    unsigned int r = (u + 0x7fffu + ((u >> 16) & 1u)) >> 16;
    return (unsigned short)r;
}
__device__ __forceinline__ float bf2f(unsigned short b) {
    return __uint_as_float(((unsigned int)b) << 16);
}

// ---------------------------------------------------------------------------
// prep: build dense normalized adjacency A (118x118 -> bf16 128x128, zero
// padded), fused LSTM biases. 1 block.
// ---------------------------------------------------------------------------
__global__ void prep_kernel(const int* __restrict__ ei,
                            const float* __restrict__ bih0, const float* __restrict__ bhh0,
                            const float* __restrict__ bih1, const float* __restrict__ bhh1,
                            float* __restrict__ bias0, float* __restrict__ bias1,
                            unsigned short* __restrict__ AbG) {
    __shared__ int sflag;
    __shared__ int ssrc[EE], sdst[EE];
    __shared__ int scount[NN];
    __shared__ float sinv[NN];
    __shared__ float Adense[NN * NN];  // 55.7 KB
    int tid = threadIdx.x;
    if (tid == 0) sflag = 0;
    __syncthreads();
    // int64-vs-int32 layout detect (values < 118 -> high words zero if int64)
    for (int i = tid; i < 2 * EE; i += blockDim.x)
        if ((i & 1) && ei[i] != 0) atomicOr(&sflag, 1);
    __syncthreads();
    bool m64 = (sflag == 0);
    for (int e = tid; e < EE; e += blockDim.x) {
        int s, d;
        if (m64) { s = ei[2 * e]; d = ei[2 * EE + 2 * e]; }
        else     { s = ei[e];     d = ei[EE + e]; }
        s = min(max(s, 0), NN - 1); d = min(max(d, 0), NN - 1);
        ssrc[e] = s; sdst[e] = d;
    }
    for (int n = tid; n < NN; n += blockDim.x) scount[n] = 0;
    for (int i = tid; i < NN * NN; i += blockDim.x) Adense[i] = 0.0f;
    __syncthreads();
    for (int e = tid; e < EE; e += blockDim.x) atomicAdd(&scount[sdst[e]], 1);
    __syncthreads();
    for (int n = tid; n < NN; n += blockDim.x) {
        float deg = 1.0f + (float)scount[n];
        sinv[n] = rsqrtf(deg);
        Adense[n * NN + n] = 1.0f / deg;   // self term h*(1/deg)
    }
    __syncthreads();
    for (int e = tid; e < EE; e += blockDim.x)
        atomicAdd(&Adense[sdst[e] * NN + ssrc[e]], sinv[ssrc[e]] * sinv[sdst[e]]);
    __syncthreads();
    // write bf16 128x128 with zero padding
    for (int i = tid; i < 128 * 128; i += blockDim.x) {
        int r = i >> 7, c = i & 127;
        AbG[i] = (r < NN && c < NN) ? f2bf(Adense[r * NN + c]) : (unsigned short)0;
    }
    for (int j = tid; j < FD; j += blockDim.x) {
        bias0[j] = bih0[j] + bhh0[j];
        bias1[j] = bih1[j] + bhh1[j];
    }
}

// ---------------------------------------------------------------------------
// W (K=128 x N=128, fp32) -> bf16 [n][k] (k contiguous) for MFMA B-frags
// ---------------------------------------------------------------------------
__global__ void convw_kernel(const float* __restrict__ W, unsigned short* __restrict__ out) {
    int i = blockIdx.x * 512 + threadIdx.x;  // 16384 total
    int n = i >> 7, k = i & 127;
    out[i] = f2bf(W[k * DD + n]);
}

// ---------------------------------------------------------------------------
// transpose (512,128) -> (128,512) so proj reads coalesced
// ---------------------------------------------------------------------------
__global__ void transpose_kernel(const float* __restrict__ in, float* __restrict__ out) {
    int idx = blockIdx.x * blockDim.x + threadIdx.x;  // 65536 total
    int j = idx >> 7, k = idx & 127;
    out[k * FD + j] = in[idx];
}

// ---------------------------------------------------------------------------
// GCN building blocks
// ---------------------------------------------------------------------------
// stage a packed 128x128 bf16 global matrix into LDS with XS stride
__device__ __forceinline__ void load_m(const unsigned short* __restrict__ src,
                                       unsigned short* __restrict__ dst, int tid) {
    const uint4* s4 = (const uint4*)src;  // 2048 chunks of 16B (8 bf16)
    for (int c = tid; c < 2048; c += 512) {
        int r = c >> 4, k8 = (c & 15) * 8;
        uint4 v = s4[c];
        *(uint4*)(dst + r * XS + k8) = v;
    }
}

// mm1: hS[n=dout][m=node] = (xb[m][k] @ wt[n][k]) packed bf16, contiguous m writes
__device__ __forceinline__ void mm_xw(const unsigned short* __restrict__ xb,
                                      const unsigned short* __restrict__ wt,
                                      unsigned short* __restrict__ hS, int tid) {
    int lane = tid & 63, w = tid >> 6;
    int lm = lane & 15, lq = lane >> 4;
    int wm = (w & 1) * 64, wn = (w >> 1) * 32;
    f32x4 acc[4][2];
#pragma unroll
    for (int mt = 0; mt < 4; ++mt)
#pragma unroll
        for (int nt = 0; nt < 2; ++nt) acc[mt][nt] = (f32x4){0.f, 0.f, 0.f, 0.f};
#pragma unroll
    for (int kb = 0; kb < 4; ++kb) {
        int ko = kb * 32 + lq * 8;
        bf16x8 b0 = *(const bf16x8*)(wt + (wn + lm) * XS + ko);
        bf16x8 b1 = *(const bf16x8*)(wt + (wn + 16 + lm) * XS + ko);
#pragma unroll
        for (int mt = 0; mt < 4; ++mt) {
            bf16x8 af = *(const bf16x8*)(xb + (wm + mt * 16 + lm) * XS + ko);
            acc[mt][0] = __builtin_amdgcn_mfma_f32_16x16x32_bf16(af, b0, acc[mt][0], 0, 0, 0);
            acc[mt][1] = __builtin_amdgcn_mfma_f32_16x16x32_bf16(af, b1, acc[mt][1], 0, 0, 0);
        }
    }
#pragma unroll
    for (int mt = 0; mt < 4; ++mt)
#pragma unroll
        for (int nt = 0; nt < 2; ++nt) {
            f32x4 a = acc[mt][nt];
            ushort4 pk;
            pk.x = f2bf(a[0]); pk.y = f2bf(a[1]); pk.z = f2bf(a[2]); pk.w = f2bf(a[3]);
            *(ushort4*)(hS + (wn + nt * 16 + lm) * XS + wm + mt * 16 + lq * 4) = pk;
        }
}

// mm2: xb[m=node][n=d] = silu(Ab[m][k] @ hS[n][k] + bias[n]) bf16 scalar writes
__device__ __forceinline__ void mm_agg(const unsigned short* __restrict__ Ab,
                                       const unsigned short* __restrict__ hS,
                                       unsigned short* __restrict__ xb,
                                       float bn0, float bn1, int tid) {
    int lane = tid & 63, w = tid >> 6;
    int lm = lane & 15, lq = lane >> 4;
    int wm = (w & 1) * 64, wn = (w >> 1) * 32;
    f32x4 acc[4][2];
#pragma unroll
    for (int mt = 0; mt < 4; ++mt)
#pragma unroll
        for (int nt = 0; nt < 2; ++nt) acc[mt][nt] = (f32x4){0.f, 0.f, 0.f, 0.f};
#pragma unroll
    for (int kb = 0; kb < 4; ++kb) {
        int ko = kb * 32 + lq * 8;
        bf16x8 b0 = *(const bf16x8*)(hS + (wn + lm) * XS + ko);
        bf16x8 b1 = *(const bf16x8*)(hS + (wn + 16 + lm) * XS + ko);
#pragma unroll
        for (int mt = 0; mt < 4; ++mt) {
            bf16x8 af = *(const bf16x8*)(Ab + (wm + mt * 16 + lm) * XS + ko);
            acc[mt][0] = __builtin_amdgcn_mfma_f32_16x16x32_bf16(af, b0, acc[mt][0], 0, 0, 0);
            acc[mt][1] = __builtin_amdgcn_mfma_f32_16x16x32_bf16(af, b1, acc[mt][1], 0, 0, 0);
        }
    }
#pragma unroll
    for (int mt = 0; mt < 4; ++mt)
#pragma unroll
        for (int nt = 0; nt < 2; ++nt) {
            float bn = nt ? bn1 : bn0;
            int col = wn + nt * 16 + lm;
#pragma unroll
            for (int i = 0; i < 4; ++i) {
                float v = silu_f(acc[mt][nt][i] + bn);
                xb[(wm + mt * 16 + lq * 4 + i) * XS + col] = f2bf(v);
            }
        }
}

__global__ __launch_bounds__(512) void gcn_kernel(
    const float* __restrict__ xg, const float* __restrict__ scale, const float* __restrict__ shift,
    const float* __restrict__ W1, const float* __restrict__ b1,
    const float* __restrict__ b2, const float* __restrict__ b3,
    const unsigned short* __restrict__ AbG,
    const unsigned short* __restrict__ Wt2g, const unsigned short* __restrict__ Wt3g,
    float* __restrict__ emb) {
    extern __shared__ char smem[];
    unsigned short* xb = (unsigned short*)smem;              // 34816 B  [node][d]
    unsigned short* hS = (unsigned short*)(smem + 34816);    // 34816 B  [d][node]
    unsigned short* Ab = (unsigned short*)(smem + 69632);    // 34816 B  [dst][src]
    unsigned short* wt = (unsigned short*)(smem + 104448);   // 34816 B  [dout][din]
    float* xinL  = (float*)(smem + 139264);                  // 354 f -> 1424 B
    float* meanS = (float*)(smem + 140688);                  // 512 f -> 2048 B (end 142736)
    int tid = threadIdx.x;
    int lane = tid & 63, w = tid >> 6;
    int g = blockIdx.x;

    // zero hS fully (NaN-poison safety for pad cols) + xb pad rows
    for (int i = tid; i < 2176; i += 512) ((uint4*)hS)[i] = (uint4){0, 0, 0, 0};
    for (int i = tid; i < 170; i += 512) ((uint4*)(xb + NN * XS))[i] = (uint4){0, 0, 0, 0};
    // stage input + A + W2
    float s0 = scale[0], s1 = scale[1], s2 = scale[2];
    float t0 = shift[0], t1 = shift[1], t2 = shift[2];
    const float* xrow = xg + (size_t)g * (NN * 3);
    for (int i = tid; i < NN * 3; i += 512) {
        int f = i % 3;
        float sc = (f == 0) ? s0 : ((f == 1) ? s1 : s2);
        float sf = (f == 0) ? t0 : ((f == 1) ? t1 : t2);
        xinL[i] = xrow[i] * sc + sf;
    }
    load_m(AbG, Ab, tid);
    load_m(Wt2g, wt, tid);
    // per-lane constants
    int lm = lane & 15;
    int wn = (w >> 1) * 32;
    int n0 = wn + lm, n1 = wn + 16 + lm;
    float b1a = b1[n0], b1b = b1[n1];
    float b2a = b2[n0], b2b = b2[n1];
    float b3a = b3[n0], b3b = b3[n1];
    int dd = lane * 2;
    float2 w10 = *(const float2*)(W1 + dd);
    float2 w11 = *(const float2*)(W1 + DD + dd);
    float2 w12 = *(const float2*)(W1 + 2 * DD + dd);
    bar_lds();
    // layer 1 (K=3): h1 -> hS[d][node], lane owns d-pair, wave-per-node
    for (int k = 0; k < 15; ++k) {
        int n = w + 8 * k;
        if (n >= NN) break;
        float x0 = xinL[n * 3], x1 = xinL[n * 3 + 1], x2 = xinL[n * 3 + 2];
        hS[dd * XS + n]       = f2bf(x0 * w10.x + x1 * w11.x + x2 * w12.x);
        hS[(dd + 1) * XS + n] = f2bf(x0 * w10.y + x1 * w11.y + x2 * w12.y);
    }
    bar_lds();
    mm_agg(Ab, hS, xb, b1a, b1b, tid);   // x1
    bar_lds();
    mm_xw(xb, wt, hS, tid);              // h2
    bar_lds();
    load_m(Wt3g, wt, tid);               // overlaps with mm_agg below
    mm_agg(Ab, hS, xb, b2a, b2b, tid);   // x2
    bar_lds();
    mm_xw(xb, wt, hS, tid);              // h3
    bar_lds();
    mm_agg(Ab, hS, xb, b3a, b3b, tid);   // x3
    bar_lds();
    // mean over nodes
    {
        int d = tid & 127, part = tid >> 7;
        int a0 = part * 30;
        int a1 = (a0 + 30 < NN) ? (a0 + 30) : NN;
        float s = 0.f;
        for (int n = a0; n < a1; ++n) s += bf2f(xb[n * XS + d]);
        meanS[part * 128 + d] = s;
    }
    bar_lds();
    if (tid < 128) {
        float s = meanS[tid] + meanS[128 + tid] + meanS[256 + tid] + meanS[384 + tid];
        emb[(size_t)g * DD + tid] = s * (1.0f / (float)NN);
    }
}

// ---------------------------------------------------------------------------
// proj: dst[g][j] = bias[j] + sum_k src[g][k] * WT[k][j]
// ---------------------------------------------------------------------------
__global__ __launch_bounds__(512) void proj_kernel(const float* __restrict__ src,
                                                   const float* __restrict__ WT,
                                                   const float* __restrict__ bias,
                                                   float* __restrict__ dst) {
    __shared__ __align__(16) float eL[DD];
    int g = blockIdx.x, tid = threadIdx.x;
    if (tid < DD) eL[tid] = src[(size_t)g * DD + tid];
    __syncthreads();
    float acc = bias[tid];
    const float* wt = WT + tid;
#pragma unroll 8
    for (int k = 0; k < DD; ++k) acc += eL[k] * wt[(size_t)k * FD];
    dst[(size_t)g * FD + tid] = acc;
}

// ---------------------------------------------------------------------------
// LSTM scan: one workgroup per batch element. Whh row j register-resident.
// lgkm-only barriers; input prefetch depth 2 (covers ~900cyc HBM latency).
// full=1: write whole h sequence; full=0: only final h.
// ---------------------------------------------------------------------------
__global__ __launch_bounds__(512, 2) void scan_kernel(const float* __restrict__ inp,
                                                      const float* __restrict__ Whh,
                                                      float* __restrict__ hout, int full) {
    __shared__ __align__(16) float sh[DD];
    __shared__ float sg[FD];
    int b = blockIdx.x, j = threadIdx.x;
    float4 wreg[32];
    const float4* wp = ((const float4*)Whh) + (size_t)j * 32;
#pragma unroll
    for (int q = 0; q < 32; ++q) wreg[q] = wp[q];
    float creg = 0.f;
    if (j < DD) sh[j] = 0.f;
    bar_lds();
    const float* ib = inp + (size_t)b * TT * FD;
    float* hb_ = hout + (size_t)b * (full ? TT * DD : DD);
    bool isg = (j >= 2 * DD) && (j < 3 * DD);
    float g0 = ib[j];
    float g1 = ib[FD + j];
    for (int t = 0; t < TT; ++t) {
        float g2 = (t + 2 < TT) ? ib[(t + 2) * FD + j] : 0.f;  // prefetch depth 2
        const float4* h4 = (const float4*)sh;
        float a0 = 0.f, a1 = 0.f, a2 = 0.f, a3 = 0.f;
#pragma unroll
        for (int q = 0; q < 32; ++q) {
            float4 hv = h4[q];
            a0 += hv.x * wreg[q].x;
            a1 += hv.y * wreg[q].y;
            a2 += hv.z * wreg[q].z;
            a3 += hv.w * wreg[q].w;
        }
        float pre = g0 + ((a0 + a1) + (a2 + a3));
        sg[j] = isg ? tanh_f(pre) : sig_f(pre);
        bar_lds();
        if (j < DD) {
            float cn = sg[DD + j] * creg + sg[j] * sg[2 * DD + j];
            creg = cn;
            float hn = sg[3 * DD + j] * tanh_f(cn);
            sh[j] = hn;
            if (full) hb_[t * DD + j] = hn;       // fire-and-forget
            else if (t == TT - 1) hb_[j] = hn;
        }
        bar_lds();
        g0 = g1; g1 = g2;
    }
}

// ---------------------------------------------------------------------------
// head MLP on final hidden state. 1 block.
// ---------------------------------------------------------------------------
__global__ void head_kernel(const float* __restrict__ hfin,
                            const float* __restrict__ hW1, const float* __restrict__ hb1,
                            const float* __restrict__ hW2, const float* __restrict__ hb2,
                            const float* __restrict__ hW3, const float* __restrict__ hb3,
                            float* __restrict__ out) {
    __shared__ float fh[BB * DD];
    __shared__ float y1[BB * DD];
    __shared__ float y2[BB * 64];
    int tid = threadIdx.x;
    for (int i = tid; i < BB * DD; i += 256) fh[i] = hfin[i];
    __syncthreads();
    for (int i = tid; i < BB * DD; i += 256) {
        int bb = i >> 7, jj = i & 127;
        float acc = hb1[jj];
        for (int k = 0; k < DD; ++k) acc += fh[(bb << 7) + k] * hW1[(k << 7) + jj];
        y1[i] = siluf_(acc);
    }
    __syncthreads();
    for (int i = tid; i < BB * 64; i += 256) {
        int bb = i >> 6, jj = i & 63;
        float acc = hb2[jj];
        for (int k = 0; k < DD; ++k) acc += y1[(bb << 7) + k] * hW2[(k << 6) + jj];
        y2[i] = siluf_(acc);
    }
    __syncthreads();
    if (tid < BB * 2) {
        int bb = tid >> 1, m = tid & 1;
        float acc = hb3[m];
        for (int k = 0; k < 64; ++k) acc += y2[(bb << 6) + k] * hW3[k * 2 + m];
        float sp = fmaxf(acc, 0.f) + log1pf(expf(-fabsf(acc)));
        out[tid] = sp + 1e-6f;
    }
}

// ---------------------------------------------------------------------------
extern "C" void kernel_launch(void* const* d_in, const int* in_sizes, int n_in,
                              void* d_out, int out_size, void* d_ws, size_t ws_size,
                              hipStream_t stream) {
    const float* snap  = (const float*)d_in[0];
    const int*   edges = (const int*)d_in[1];
    const float* scale = (const float*)d_in[2];
    const float* shift = (const float*)d_in[3];
    const float* W1 = (const float*)d_in[4];
    const float* b1 = (const float*)d_in[5];
    const float* W2 = (const float*)d_in[6];
    const float* b2 = (const float*)d_in[7];
    const float* W3 = (const float*)d_in[8];
    const float* b3 = (const float*)d_in[9];
    const float* Wih0 = (const float*)d_in[10];
    const float* Whh0 = (const float*)d_in[11];
    const float* bih0 = (const float*)d_in[12];
    const float* bhh0 = (const float*)d_in[13];
    const float* Wih1 = (const float*)d_in[14];
    const float* Whh1 = (const float*)d_in[15];
    const float* bih1 = (const float*)d_in[16];
    const float* bhh1 = (const float*)d_in[17];
    const float* hW1 = (const float*)d_in[18];
    const float* hb1 = (const float*)d_in[19];
    const float* hW2 = (const float*)d_in[20];
    const float* hb2 = (const float*)d_in[21];
    const float* hW3 = (const float*)d_in[22];
    const float* hb3 = (const float*)d_in[23];

    // workspace carve (float indices); ~6.9 MB
    float* ws = (float*)d_ws;
    float* bias0 = ws + 0;                        // 512
    float* bias1 = ws + 512;                      // 512
    unsigned short* AbG  = (unsigned short*)(ws + 1024);   // 16384 bf16 = 8192 f
    unsigned short* Wt2g = (unsigned short*)(ws + 9216);   // 8192 f
    unsigned short* Wt3g = (unsigned short*)(ws + 17408);  // 8192 f
    float* WT0   = ws + 25600;                    // 65536
    float* WT1   = ws + 91136;                    // 65536
    float* emb   = ws + 156672;                   // 262144
    float* inp   = ws + 418816;                   // 1048576 (both LSTM layers)
    float* h0seq = ws + 1467392;                  // 262144
    float* hfin  = ws + 1729536;                  // 1024

    const int smem_gcn = 142736;
    hipFuncSetAttribute((const void*)gcn_kernel,
                        hipFuncAttributeMaxDynamicSharedMemorySize, smem_gcn);

    prep_kernel<<<1, 256, 0, stream>>>(edges, bih0, bhh0, bih1, bhh1,
                                       bias0, bias1, AbG);
    convw_kernel<<<32, 512, 0, stream>>>(W2, Wt2g);
    convw_kernel<<<32, 512, 0, stream>>>(W3, Wt3g);
    transpose_kernel<<<128, 512, 0, stream>>>(Wih0, WT0);
    transpose_kernel<<<128, 512, 0, stream>>>(Wih1, WT1);
    gcn_kernel<<<GG, 512, smem_gcn, stream>>>(snap, scale, shift, W1, b1, b2, b3,
                                              AbG, Wt2g, Wt3g, emb);
    proj_kernel<<<GG, 512, 0, stream>>>(emb, WT0, bias0, inp);
    scan_kernel<<<BB, 512, 0, stream>>>(inp, Whh0, h0seq, 1);
    proj_kernel<<<GG, 512, 0, stream>>>(h0seq, WT1, bias1, inp);
    scan_kernel<<<BB, 512, 0, stream>>>(inp, Whh1, hfin, 0);
    head_kernel<<<1, 256, 0, stream>>>(hfin, hW1, hb1, hW2, hb2, hW3, hb3, (float*)d_out);
}

// Round 6
// 609.723 us; speedup vs baseline: 2.7001x; 1.1649x over previous
//
#include <hip/hip_runtime.h>
#include <math.h>

// Problem constants
#define NN 118   // nodes
#define EE 372   // edges
#define GG 2048  // B*T
#define DD 128   // hidden
#define TT 256   // seq len
#define BB 8     // batch
#define FD 512   // 4*D

// LDS stride for bf16 matrices (rows 16B-aligned, 2-way-max bank aliasing)
#define XS 136

typedef short bf16x8 __attribute__((ext_vector_type(8)));
typedef float f32x4  __attribute__((ext_vector_type(4)));
typedef _Float16 f16x2 __attribute__((ext_vector_type(2)));

__device__ __forceinline__ float frcp_(float x) { return __builtin_amdgcn_rcpf(x); }
__device__ __forceinline__ float sig_f(float x) { return frcp_(1.0f + __expf(-x)); }
__device__ __forceinline__ float tanh_f(float x) { return 1.0f - 2.0f * frcp_(__expf(2.0f * x) + 1.0f); }
__device__ __forceinline__ float silu_f(float x) { return x * frcp_(1.0f + __expf(-x)); }
__device__ __forceinline__ float siluf_(float x) { return x / (1.0f + expf(-x)); }

// f16-pair dot with fp32 accumulate (v_dot2_f32_f16); scalar fallback.
__device__ __forceinline__ float fdot2_(unsigned int a, unsigned int b, float c) {
#if defined(__has_builtin) && __has_builtin(__builtin_amdgcn_fdot2)
    return __builtin_amdgcn_fdot2(__builtin_bit_cast(f16x2, a),
                                  __builtin_bit_cast(f16x2, b), c, false);
#else
    f16x2 x = __builtin_bit_cast(f16x2, a), y = __builtin_bit_cast(f16x2, b);
    return c + (float)x[0] * (float)y[0] + (float)x[1] * (float)y[1];
#endif
}

// Barrier draining only LDS ops (lgkmcnt), not vmcnt: global stores stay
// fire-and-forget, prefetch loads stay in flight. Safe: all cross-thread data
// flows through LDS (global->VGPR uses get compiler vmcnt waits).
__device__ __forceinline__ void bar_lds() {
    asm volatile("s_waitcnt lgkmcnt(0)\n\ts_barrier" ::: "memory");
}

__device__ __forceinline__ unsigned short f2bf(float x) {
    unsigned int u = __float_as_uint(x);
    unsigned int r = (u + 0x7fffu + ((u >> 16) & 1u)) >> 16;
    return (unsigned short)r;
}
__device__ __forceinline__ float bf2f(unsigned short b) {
    return __uint_as_float(((unsigned int)b) << 16);
}

// ---------------------------------------------------------------------------
// prep: dense normalized adjacency A -> bf16 128x128 (zero padded), fused
// LSTM biases. 1 block.
// ---------------------------------------------------------------------------
__global__ void prep_kernel(const int* __restrict__ ei,
                            const float* __restrict__ bih0, const float* __restrict__ bhh0,
                            const float* __restrict__ bih1, const float* __restrict__ bhh1,
                            float* __restrict__ bias0, float* __restrict__ bias1,
                            unsigned short* __restrict__ AbG) {
    __shared__ int sflag;
    __shared__ int ssrc[EE], sdst[EE];
    __shared__ int scount[NN];
    __shared__ float sinv[NN];
    __shared__ float Adense[NN * NN];  // 55.7 KB
    int tid = threadIdx.x;
    if (tid == 0) sflag = 0;
    __syncthreads();
    // int64-vs-int32 layout detect (values < 118 -> high words zero if int64)
    for (int i = tid; i < 2 * EE; i += blockDim.x)
        if ((i & 1) && ei[i] != 0) atomicOr(&sflag, 1);
    __syncthreads();
    bool m64 = (sflag == 0);
    for (int e = tid; e < EE; e += blockDim.x) {
        int s, d;
        if (m64) { s = ei[2 * e]; d = ei[2 * EE + 2 * e]; }
        else     { s = ei[e];     d = ei[EE + e]; }
        s = min(max(s, 0), NN - 1); d = min(max(d, 0), NN - 1);
        ssrc[e] = s; sdst[e] = d;
    }
    for (int n = tid; n < NN; n += blockDim.x) scount[n] = 0;
    for (int i = tid; i < NN * NN; i += blockDim.x) Adense[i] = 0.0f;
    __syncthreads();
    for (int e = tid; e < EE; e += blockDim.x) atomicAdd(&scount[sdst[e]], 1);
    __syncthreads();
    for (int n = tid; n < NN; n += blockDim.x) {
        float deg = 1.0f + (float)scount[n];
        sinv[n] = rsqrtf(deg);
        Adense[n * NN + n] = 1.0f / deg;   // self term h*(1/deg)
    }
    __syncthreads();
    for (int e = tid; e < EE; e += blockDim.x)
        atomicAdd(&Adense[sdst[e] * NN + ssrc[e]], sinv[ssrc[e]] * sinv[sdst[e]]);
    __syncthreads();
    for (int i = tid; i < 128 * 128; i += blockDim.x) {
        int r = i >> 7, c = i & 127;
        AbG[i] = (r < NN && c < NN) ? f2bf(Adense[r * NN + c]) : (unsigned short)0;
    }
    for (int j = tid; j < FD; j += blockDim.x) {
        bias0[j] = bih0[j] + bhh0[j];
        bias1[j] = bih1[j] + bhh1[j];
    }
}

// ---------------------------------------------------------------------------
// W (K=128 x N=128, fp32) -> bf16 [n][k] (k contiguous) for MFMA B-frags
// ---------------------------------------------------------------------------
__global__ void convw_kernel(const float* __restrict__ W, unsigned short* __restrict__ out) {
    int i = blockIdx.x * 512 + threadIdx.x;  // 16384 total
    int n = i >> 7, k = i & 127;
    out[i] = f2bf(W[k * DD + n]);
}

// ---------------------------------------------------------------------------
// Whh (512x128 fp32, row-major) -> packed f16 pairs [512][64] uint
// ---------------------------------------------------------------------------
__global__ void convh_kernel(const float* __restrict__ W, unsigned int* __restrict__ out) {
    int i = blockIdx.x * 512 + threadIdx.x;  // 32768 total
    float a = W[2 * i], b = W[2 * i + 1];
    unsigned short lo = __builtin_bit_cast(unsigned short, (_Float16)a);
    unsigned short hi = __builtin_bit_cast(unsigned short, (_Float16)b);
    out[i] = (unsigned int)lo | ((unsigned int)hi << 16);
}

// ---------------------------------------------------------------------------
// transpose (512,128) -> (128,512) so proj reads coalesced
// ---------------------------------------------------------------------------
__global__ void transpose_kernel(const float* __restrict__ in, float* __restrict__ out) {
    int idx = blockIdx.x * blockDim.x + threadIdx.x;  // 65536 total
    int j = idx >> 7, k = idx & 127;
    out[k * FD + j] = in[idx];
}

// ---------------------------------------------------------------------------
// GCN building blocks
// ---------------------------------------------------------------------------
__device__ __forceinline__ void load_m(const unsigned short* __restrict__ src,
                                       unsigned short* __restrict__ dst, int tid) {
    const uint4* s4 = (const uint4*)src;  // 2048 chunks of 16B (8 bf16)
    for (int c = tid; c < 2048; c += 512) {
        int r = c >> 4, k8 = (c & 15) * 8;
        uint4 v = s4[c];
        *(uint4*)(dst + r * XS + k8) = v;
    }
}

// mm1: hS[n=dout][m=node] = (xb[m][k] @ wt[n][k]) packed bf16
__device__ __forceinline__ void mm_xw(const unsigned short* __restrict__ xb,
                                      const unsigned short* __restrict__ wt,
                                      unsigned short* __restrict__ hS, int tid) {
    int lane = tid & 63, w = tid >> 6;
    int lm = lane & 15, lq = lane >> 4;
    int wm = (w & 1) * 64, wn = (w >> 1) * 32;
    f32x4 acc[4][2];
#pragma unroll
    for (int mt = 0; mt < 4; ++mt)
#pragma unroll
        for (int nt = 0; nt < 2; ++nt) acc[mt][nt] = (f32x4){0.f, 0.f, 0.f, 0.f};
#pragma unroll
    for (int kb = 0; kb < 4; ++kb) {
        int ko = kb * 32 + lq * 8;
        bf16x8 b0 = *(const bf16x8*)(wt + (wn + lm) * XS + ko);
        bf16x8 b1 = *(const bf16x8*)(wt + (wn + 16 + lm) * XS + ko);
#pragma unroll
        for (int mt = 0; mt < 4; ++mt) {
            bf16x8 af = *(const bf16x8*)(xb + (wm + mt * 16 + lm) * XS + ko);
            acc[mt][0] = __builtin_amdgcn_mfma_f32_16x16x32_bf16(af, b0, acc[mt][0], 0, 0, 0);
            acc[mt][1] = __builtin_amdgcn_mfma_f32_16x16x32_bf16(af, b1, acc[mt][1], 0, 0, 0);
        }
    }
#pragma unroll
    for (int mt = 0; mt < 4; ++mt)
#pragma unroll
        for (int nt = 0; nt < 2; ++nt) {
            f32x4 a = acc[mt][nt];
            ushort4 pk;
            pk.x = f2bf(a[0]); pk.y = f2bf(a[1]); pk.z = f2bf(a[2]); pk.w = f2bf(a[3]);
            *(ushort4*)(hS + (wn + nt * 16 + lm) * XS + wm + mt * 16 + lq * 4) = pk;
        }
}

// mm2: xb[m=node][n=d] = silu(Ab[m][k] @ hS[n][k] + bias[n]) bf16
__device__ __forceinline__ void mm_agg(const unsigned short* __restrict__ Ab,
                                       const unsigned short* __restrict__ hS,
                                       unsigned short* __restrict__ xb,
                                       float bn0, float bn1, int tid) {
    int lane = tid & 63, w = tid >> 6;
    int lm = lane & 15, lq = lane >> 4;
    int wm = (w & 1) * 64, wn = (w >> 1) * 32;
    f32x4 acc[4][2];
#pragma unroll
    for (int mt = 0; mt < 4; ++mt)
#pragma unroll
        for (int nt = 0; nt < 2; ++nt) acc[mt][nt] = (f32x4){0.f, 0.f, 0.f, 0.f};
#pragma unroll
    for (int kb = 0; kb < 4; ++kb) {
        int ko = kb * 32 + lq * 8;
        bf16x8 b0 = *(const bf16x8*)(hS + (wn + lm) * XS + ko);
        bf16x8 b1 = *(const bf16x8*)(hS + (wn + 16 + lm) * XS + ko);
#pragma unroll
        for (int mt = 0; mt < 4; ++mt) {
            bf16x8 af = *(const bf16x8*)(Ab + (wm + mt * 16 + lm) * XS + ko);
            acc[mt][0] = __builtin_amdgcn_mfma_f32_16x16x32_bf16(af, b0, acc[mt][0], 0, 0, 0);
            acc[mt][1] = __builtin_amdgcn_mfma_f32_16x16x32_bf16(af, b1, acc[mt][1], 0, 0, 0);
        }
    }
#pragma unroll
    for (int mt = 0; mt < 4; ++mt)
#pragma unroll
        for (int nt = 0; nt < 2; ++nt) {
            float bn = nt ? bn1 : bn0;
            int col = wn + nt * 16 + lm;
#pragma unroll
            for (int i = 0; i < 4; ++i) {
                float v = silu_f(acc[mt][nt][i] + bn);
                xb[(wm + mt * 16 + lq * 4 + i) * XS + col] = f2bf(v);
            }
        }
}

__global__ __launch_bounds__(512) void gcn_kernel(
    const float* __restrict__ xg, const float* __restrict__ scale, const float* __restrict__ shift,
    const float* __restrict__ W1, const float* __restrict__ b1,
    const float* __restrict__ b2, const float* __restrict__ b3,
    const unsigned short* __restrict__ AbG,
    const unsigned short* __restrict__ Wt2g, const unsigned short* __restrict__ Wt3g,
    float* __restrict__ emb) {
    extern __shared__ char smem[];
    unsigned short* xb = (unsigned short*)smem;              // 34816 B  [node][d]
    unsigned short* hS = (unsigned short*)(smem + 34816);    // 34816 B  [d][node]
    unsigned short* Ab = (unsigned short*)(smem + 69632);    // 34816 B  [dst][src]
    unsigned short* wt = (unsigned short*)(smem + 104448);   // 34816 B  [dout][din]
    float* xinL  = (float*)(smem + 139264);                  // 354 f
    float* meanS = (float*)(smem + 140688);                  // 512 f (end 142736)
    int tid = threadIdx.x;
    int lane = tid & 63, w = tid >> 6;
    int g = blockIdx.x;

    for (int i = tid; i < 2176; i += 512) ((uint4*)hS)[i] = (uint4){0, 0, 0, 0};
    for (int i = tid; i < 170; i += 512) ((uint4*)(xb + NN * XS))[i] = (uint4){0, 0, 0, 0};
    float s0 = scale[0], s1 = scale[1], s2 = scale[2];
    float t0 = shift[0], t1 = shift[1], t2 = shift[2];
    const float* xrow = xg + (size_t)g * (NN * 3);
    for (int i = tid; i < NN * 3; i += 512) {
        int f = i % 3;
        float sc = (f == 0) ? s0 : ((f == 1) ? s1 : s2);
        float sf = (f == 0) ? t0 : ((f == 1) ? t1 : t2);
        xinL[i] = xrow[i] * sc + sf;
    }
    load_m(AbG, Ab, tid);
    load_m(Wt2g, wt, tid);
    int lm = lane & 15;
    int wn = (w >> 1) * 32;
    int n0 = wn + lm, n1 = wn + 16 + lm;
    float b1a = b1[n0], b1b = b1[n1];
    float b2a = b2[n0], b2b = b2[n1];
    float b3a = b3[n0], b3b = b3[n1];
    int dd = lane * 2;
    float2 w10 = *(const float2*)(W1 + dd);
    float2 w11 = *(const float2*)(W1 + DD + dd);
    float2 w12 = *(const float2*)(W1 + 2 * DD + dd);
    bar_lds();
    for (int k = 0; k < 15; ++k) {
        int n = w + 8 * k;
        if (n >= NN) break;
        float x0 = xinL[n * 3], x1 = xinL[n * 3 + 1], x2 = xinL[n * 3 + 2];
        hS[dd * XS + n]       = f2bf(x0 * w10.x + x1 * w11.x + x2 * w12.x);
        hS[(dd + 1) * XS + n] = f2bf(x0 * w10.y + x1 * w11.y + x2 * w12.y);
    }
    bar_lds();
    mm_agg(Ab, hS, xb, b1a, b1b, tid);   // x1
    bar_lds();
    mm_xw(xb, wt, hS, tid);              // h2
    bar_lds();
    load_m(Wt3g, wt, tid);
    mm_agg(Ab, hS, xb, b2a, b2b, tid);   // x2
    bar_lds();
    mm_xw(xb, wt, hS, tid);              // h3
    bar_lds();
    mm_agg(Ab, hS, xb, b3a, b3b, tid);   // x3
    bar_lds();
    {
        int d = tid & 127, part = tid >> 7;
        int a0 = part * 30;
        int a1 = (a0 + 30 < NN) ? (a0 + 30) : NN;
        float s = 0.f;
        for (int n = a0; n < a1; ++n) s += bf2f(xb[n * XS + d]);
        meanS[part * 128 + d] = s;
    }
    bar_lds();
    if (tid < 128) {
        float s = meanS[tid] + meanS[128 + tid] + meanS[256 + tid] + meanS[384 + tid];
        emb[(size_t)g * DD + tid] = s * (1.0f / (float)NN);
    }
}

// ---------------------------------------------------------------------------
// proj: dst[g][j] = bias[j] + sum_k src[g][k] * WT[k][j]
// ---------------------------------------------------------------------------
__global__ __launch_bounds__(512) void proj_kernel(const float* __restrict__ src,
                                                   const float* __restrict__ WT,
                                                   const float* __restrict__ bias,
                                                   float* __restrict__ dst) {
    __shared__ __align__(16) float eL[DD];
    int g = blockIdx.x, tid = threadIdx.x;
    if (tid < DD) eL[tid] = src[(size_t)g * DD + tid];
    __syncthreads();
    float acc = bias[tid];
    const float* wt = WT + tid;
#pragma unroll 8
    for (int k = 0; k < DD; ++k) acc += eL[k] * wt[(size_t)k * FD];
    dst[(size_t)g * FD + tid] = acc;
}

// ---------------------------------------------------------------------------
// LSTM scan: one workgroup per batch element. Whh row j register-resident as
// f16 pairs; recurrent GEMV via v_dot2_f32_f16 (fp32 accumulate); h kept in
// LDS as f16. c/h update computed redundantly by all 4 gate-groups (kills the
// divergent tail). lgkm-only barriers. full=1: whole h seq; full=0: final h.
// ---------------------------------------------------------------------------
__global__ __launch_bounds__(512) void scan_kernel(const float* __restrict__ inp,
                                                   const unsigned int* __restrict__ Wh16,
                                                   float* __restrict__ hout, int full) {
    __shared__ __align__(16) unsigned int sh2[64];  // h as 64 f16-pairs
    __shared__ float sg[FD];                        // activated gates
    int b = blockIdx.x, j = threadIdx.x;
    uint4 wreg[16];
    const uint4* wp = ((const uint4*)Wh16) + (size_t)j * 16;
#pragma unroll
    for (int q = 0; q < 16; ++q) wreg[q] = wp[q];
    float creg = 0.f;
    if (j < 64) sh2[j] = 0u;
    bar_lds();
    const float* ib = inp + (size_t)b * TT * FD;
    float* hb_ = hout + (size_t)b * (full ? TT * DD : DD);
    bool isg = (j >= 2 * DD) && (j < 3 * DD);
    int d = j & 127;
    float g0 = ib[j];
    float g1 = ib[FD + j];
    float g2 = ib[2 * FD + j];
    for (int t = 0; t < TT; ++t) {
        float g3 = (t + 3 < TT) ? ib[(t + 3) * FD + j] : 0.f;  // prefetch depth 3
        const uint4* h4 = (const uint4*)sh2;
        float acc = g0;
#pragma unroll
        for (int q = 0; q < 16; ++q) {
            uint4 hv = h4[q];
            uint4 wv = wreg[q];
            acc = fdot2_(wv.x, hv.x, acc);
            acc = fdot2_(wv.y, hv.y, acc);
            acc = fdot2_(wv.z, hv.z, acc);
            acc = fdot2_(wv.w, hv.w, acc);
        }
        sg[j] = isg ? tanh_f(acc) : sig_f(acc);
        bar_lds();
        // redundant per-group update (4 identical creg copies stay in sync)
        float iv = sg[d], fv = sg[DD + d], gv = sg[2 * DD + d], ov = sg[3 * DD + d];
        float cn = fv * creg + iv * gv;
        creg = cn;
        float hn = ov * tanh_f(cn);
        if (j < DD) {
            ((_Float16*)sh2)[j] = (_Float16)hn;
            if (full) hb_[t * DD + j] = hn;          // fire-and-forget
            else if (t == TT - 1) hb_[j] = hn;
        }
        bar_lds();
        g0 = g1; g1 = g2; g2 = g3;
    }
}

// ---------------------------------------------------------------------------
// head MLP on final hidden state. 1 block.
// ---------------------------------------------------------------------------
__global__ void head_kernel(const float* __restrict__ hfin,
                            const float* __restrict__ hW1, const float* __restrict__ hb1,
                            const float* __restrict__ hW2, const float* __restrict__ hb2,
                            const float* __restrict__ hW3, const float* __restrict__ hb3,
                            float* __restrict__ out) {
    __shared__ float fh[BB * DD];
    __shared__ float y1[BB * DD];
    __shared__ float y2[BB * 64];
    int tid = threadIdx.x;
    for (int i = tid; i < BB * DD; i += 256) fh[i] = hfin[i];
    __syncthreads();
    for (int i = tid; i < BB * DD; i += 256) {
        int bb = i >> 7, jj = i & 127;
        float acc = hb1[jj];
        for (int k = 0; k < DD; ++k) acc += fh[(bb << 7) + k] * hW1[(k << 7) + jj];
        y1[i] = siluf_(acc);
    }
    __syncthreads();
    for (int i = tid; i < BB * 64; i += 256) {
        int bb = i >> 6, jj = i & 63;
        float acc = hb2[jj];
        for (int k = 0; k < DD; ++k) acc += y1[(bb << 7) + k] * hW2[(k << 6) + jj];
        y2[i] = siluf_(acc);
    }
    __syncthreads();
    if (tid < BB * 2) {
        int bb = tid >> 1, m = tid & 1;
        float acc = hb3[m];
        for (int k = 0; k < 64; ++k) acc += y2[(bb << 6) + k] * hW3[k * 2 + m];
        float sp = fmaxf(acc, 0.f) + log1pf(expf(-fabsf(acc)));
        out[tid] = sp + 1e-6f;
    }
}

// ---------------------------------------------------------------------------
extern "C" void kernel_launch(void* const* d_in, const int* in_sizes, int n_in,
                              void* d_out, int out_size, void* d_ws, size_t ws_size,
                              hipStream_t stream) {
    const float* snap  = (const float*)d_in[0];
    const int*   edges = (const int*)d_in[1];
    const float* scale = (const float*)d_in[2];
    const float* shift = (const float*)d_in[3];
    const float* W1 = (const float*)d_in[4];
    const float* b1 = (const float*)d_in[5];
    const float* W2 = (const float*)d_in[6];
    const float* b2 = (const float*)d_in[7];
    const float* W3 = (const float*)d_in[8];
    const float* b3 = (const float*)d_in[9];
    const float* Wih0 = (const float*)d_in[10];
    const float* Whh0 = (const float*)d_in[11];
    const float* bih0 = (const float*)d_in[12];
    const float* bhh0 = (const float*)d_in[13];
    const float* Wih1 = (const float*)d_in[14];
    const float* Whh1 = (const float*)d_in[15];
    const float* bih1 = (const float*)d_in[16];
    const float* bhh1 = (const float*)d_in[17];
    const float* hW1 = (const float*)d_in[18];
    const float* hb1 = (const float*)d_in[19];
    const float* hW2 = (const float*)d_in[20];
    const float* hb2 = (const float*)d_in[21];
    const float* hW3 = (const float*)d_in[22];
    const float* hb3 = (const float*)d_in[23];

    // workspace carve (float indices); ~7.2 MB
    float* ws = (float*)d_ws;
    float* bias0 = ws + 0;                        // 512
    float* bias1 = ws + 512;                      // 512
    unsigned short* AbG  = (unsigned short*)(ws + 1024);   // 8192 f
    unsigned short* Wt2g = (unsigned short*)(ws + 9216);   // 8192 f
    unsigned short* Wt3g = (unsigned short*)(ws + 17408);  // 8192 f
    float* WT0 = ws + 25600;                      // 65536
    float* WT1 = ws + 91136;                      // 65536
    unsigned int* Wh16_0 = (unsigned int*)(ws + 156672);   // 32768
    unsigned int* Wh16_1 = (unsigned int*)(ws + 189440);   // 32768
    float* emb   = ws + 222208;                   // 262144
    float* inp   = ws + 484352;                   // 1048576 (both LSTM layers)
    float* h0seq = ws + 1532928;                  // 262144
    float* hfin  = ws + 1795072;                  // 1024

    const int smem_gcn = 142736;
    hipFuncSetAttribute((const void*)gcn_kernel,
                        hipFuncAttributeMaxDynamicSharedMemorySize, smem_gcn);

    prep_kernel<<<1, 256, 0, stream>>>(edges, bih0, bhh0, bih1, bhh1,
                                       bias0, bias1, AbG);
    convw_kernel<<<32, 512, 0, stream>>>(W2, Wt2g);
    convw_kernel<<<32, 512, 0, stream>>>(W3, Wt3g);
    convh_kernel<<<64, 512, 0, stream>>>(Whh0, Wh16_0);
    convh_kernel<<<64, 512, 0, stream>>>(Whh1, Wh16_1);
    transpose_kernel<<<128, 512, 0, stream>>>(Wih0, WT0);
    transpose_kernel<<<128, 512, 0, stream>>>(Wih1, WT1);
    gcn_kernel<<<GG, 512, smem_gcn, stream>>>(snap, scale, shift, W1, b1, b2, b3,
                                              AbG, Wt2g, Wt3g, emb);
    proj_kernel<<<GG, 512, 0, stream>>>(emb, WT0, bias0, inp);
    scan_kernel<<<BB, 512, 0, stream>>>(inp, Wh16_0, h0seq, 1);
    proj_kernel<<<GG, 512, 0, stream>>>(h0seq, WT1, bias1, inp);
    scan_kernel<<<BB, 512, 0, stream>>>(inp, Wh16_1, hfin, 0);
    head_kernel<<<1, 256, 0, stream>>>(hfin, hW1, hb1, hW2, hb2, hW3, hb3, (float*)d_out);
}